// Round 10
// baseline (391.090 us; speedup 1.0000x reference)
//
#include <hip/hip_runtime.h>
#include <math.h>
#include <stdint.h>

#define B_ROWS 2048
#define D_DIM  512
#define V_COLS 32000
#define BM 128
#define BN 128
#define BK 64
#define KSTEPS (D_DIM / BK)             // 8
#define NCT    (V_COLS / BN)            // 250 col tiles
#define NACT   (NCT * (B_ROWS / BM))    // 4000 active blocks
#define S_SC   30.0f
#define COS_M  0.8775825618903728f      // cos(0.5)
#define SIN_M  0.479425538604203f       // sin(0.5)

typedef float f32x4 __attribute__((ext_vector_type(4)));
typedef long  i64x2 __attribute__((ext_vector_type(2)));

__device__ __forceinline__ void load16_to_lds(const void* g, void* l) {
  __builtin_amdgcn_global_load_lds(
      (__attribute__((address_space(1))) void*)(g),
      (__attribute__((address_space(3))) void*)(l),
      16, 0, 0);
}

// ---------- kernel 1: fused row L2-normalize (x,W) fp32 -> fp8 e4m3, + zero rowsum/done ----------
__global__ void fused_norm_kernel(const float* __restrict__ x,
                                  const float* __restrict__ W,
                                  uint8_t* __restrict__ nx,
                                  uint8_t* __restrict__ nw,
                                  float* __restrict__ rowsum,
                                  int* __restrict__ done) {
  if (blockIdx.x == 0 && threadIdx.x == 0) *done = 0;
  if (blockIdx.x < B_ROWS / 256) rowsum[blockIdx.x * 256 + threadIdx.x] = 0.f;
  const int lane = threadIdx.x & 63;
  const int wave = threadIdx.x >> 6;
  const int gr   = blockIdx.x * 4 + wave;
  const float* src;
  uint8_t* dst;
  if (gr < B_ROWS) {
    src = x + (size_t)gr * D_DIM;
    dst = nx + (size_t)gr * D_DIM;
  } else {
    src = W + (size_t)(gr - B_ROWS) * D_DIM;
    dst = nw + (size_t)(gr - B_ROWS) * D_DIM;
  }
  const float4* r4 = (const float4*)src;
  float4 v0 = r4[2 * lane];
  float4 v1 = r4[2 * lane + 1];
  float ss = v0.x*v0.x + v0.y*v0.y + v0.z*v0.z + v0.w*v0.w
           + v1.x*v1.x + v1.y*v1.y + v1.z*v1.z + v1.w*v1.w;
  #pragma unroll
  for (int off = 32; off >= 1; off >>= 1) ss += __shfl_xor(ss, off, 64);
  float inv = 1.0f / fmaxf(sqrtf(ss), 1e-12f);
  int p0 = __builtin_amdgcn_cvt_pk_fp8_f32(v0.x * inv, v0.y * inv, 0, false);
  p0     = __builtin_amdgcn_cvt_pk_fp8_f32(v0.z * inv, v0.w * inv, p0, true);
  int p1 = __builtin_amdgcn_cvt_pk_fp8_f32(v1.x * inv, v1.y * inv, 0, false);
  p1     = __builtin_amdgcn_cvt_pk_fp8_f32(v1.z * inv, v1.w * inv, p1, true);
  ((int2*)dst)[lane] = make_int2(p0, p1);
}

// ---------- kernel 2: fp8 GEMM (nx @ nW^T), BK=64, b128 double-K frags, fused finish ----------
// R4 skeleton (proven): 2-barrier dbuf K-loop, XCD-exclusive grid swizzle (FETCH 25 MB),
// XOR bank swizzle (measured 0 conflicts), fixed-shift softmax epilogue + rowsum atomics.
// fp8 + BK=64 -> each ds_read_b128 feeds TWO MFMAs (low/high 8 B) under a K-window
// permutation applied identically to A and B (contraction order-invariant): per
// lane-quad q, MFMA h contracts global k-bytes 16q+8h..16q+8h+7.
// 8 LDS reads + 32 MFMA per wave-step (vs R4: 8 reads + 16 MFMA); 8 barrier-pairs (vs 16).
// Finish fused via device-scope done counter (threadfence release/acquire; no spin).
__global__ __launch_bounds__(256, 4)
void arc_gemm_kernel(const uint8_t* __restrict__ nx,
                     const uint8_t* __restrict__ nw,
                     const int* __restrict__ labels,
                     float* __restrict__ rowsum,
                     float* __restrict__ lbl_logit,
                     int* __restrict__ done,
                     float* __restrict__ out) {
  __shared__ uint8_t sA[2][BM * BK];   // 2 x 8 KB
  __shared__ uint8_t sB[2][BN * BK];   // 2 x 8 KB
  __shared__ int   isLast;
  __shared__ float ws4[4];

  const int id = blockIdx.x;
  const int ct = ((id >> 7) << 3) | (id & 7);
  if (ct >= NCT) return;
  const int rt = (id >> 3) & 15;
  const int m0 = rt * BM;
  const int n0 = ct * BN;

  const int tid  = threadIdx.x;
  const int wave = tid >> 6;
  const int lane = tid & 63;
  const int wm   = wave >> 1;
  const int wn   = wave & 1;
  const int quad = lane >> 4;
  const int l16  = lane & 15;

  // staging: inst i covers rows i*64 + (tid>>2); slot tid&3 <- global 16B chunk jg.
  // ((64+r)>>1)&3 == (r>>1)&3, so jg is shared by both insts.
  const int srow = tid >> 2;
  const int jg   = (tid & 3) ^ ((srow >> 1) & 3);
  const uint8_t* gA = nx + (size_t)(m0 + srow) * D_DIM + jg * 16;
  const uint8_t* gB = nw + (size_t)(n0 + srow) * D_DIM + jg * 16;
  const int ldsOff0 = wave * 1024;          // wave-uniform LDS byte bases
  const int ldsOff1 = 4096 + wave * 1024;

  // frag reads: row stride 64 B, 16B slot XOR swizzle (identical bank math to R4's
  // measured-zero-conflict pattern)
  const int cSlot = (quad ^ ((l16 >> 1) & 3)) << 4;
  const int aBase = (wm * 64 + l16) * BK + cSlot;   // + mi*16*BK
  const int bBase = (wn * 64 + l16) * BK + cSlot;   // + ni*16*BK

  f32x4 acc[4][4];
  #pragma unroll
  for (int i = 0; i < 4; ++i)
    #pragma unroll
    for (int j = 0; j < 4; ++j) acc[i][j] = (f32x4){0.f, 0.f, 0.f, 0.f};

  // prologue: tile 0 -> buf 0
  load16_to_lds(gA,              &sA[0][ldsOff0]);
  load16_to_lds(gA + 64 * D_DIM, &sA[0][ldsOff1]);
  load16_to_lds(gB,              &sB[0][ldsOff0]);
  load16_to_lds(gB + 64 * D_DIM, &sB[0][ldsOff1]);

  #pragma unroll
  for (int ks = 0; ks < KSTEPS; ++ks) {
    __syncthreads();                          // prev compute done before overwrite
    if (ks + 1 < KSTEPS) {
      const int off = (ks + 1) * BK;
      const int nb  = (ks + 1) & 1;
      load16_to_lds(gA + off,              &sA[nb][ldsOff0]);
      load16_to_lds(gA + 64 * D_DIM + off, &sA[nb][ldsOff1]);
      load16_to_lds(gB + off,              &sB[nb][ldsOff0]);
      load16_to_lds(gB + 64 * D_DIM + off, &sB[nb][ldsOff1]);
    }
    __syncthreads();                          // tile ks resident

    const uint8_t* bA = sA[ks & 1];
    const uint8_t* bB = sB[ks & 1];
    i64x2 a2[4];
    #pragma unroll
    for (int mi = 0; mi < 4; ++mi)
      a2[mi] = *(const i64x2*)(bA + aBase + mi * 16 * BK);
    #pragma unroll
    for (int ni = 0; ni < 4; ++ni) {
      const i64x2 b2 = *(const i64x2*)(bB + bBase + ni * 16 * BK);
      #pragma unroll
      for (int mi = 0; mi < 4; ++mi) {
        acc[mi][ni] = __builtin_amdgcn_mfma_f32_16x16x32_fp8_fp8(a2[mi][0], b2[0], acc[mi][ni], 0, 0, 0);
        acc[mi][ni] = __builtin_amdgcn_mfma_f32_16x16x32_fp8_fp8(a2[mi][1], b2[1], acc[mi][ni], 0, 0, 0);
      }
    }
  }

  // Epilogue (R4-proven). C/D layout: col = lane&15, row = quad*4 + reg.
  const int lblv = labels[m0 + wm * 64 + lane];
  #pragma unroll
  for (int mi = 0; mi < 4; ++mi) {
    #pragma unroll
    for (int r = 0; r < 4; ++r) {
      const int rw   = mi * 16 + quad * 4 + r;
      const int grow = m0 + wm * 64 + rw;
      const int lbl  = __shfl(lblv, rw, 64);
      float rsum = 0.f;
      #pragma unroll
      for (int ni = 0; ni < 4; ++ni) {
        float c = acc[mi][ni][r];
        const int gcol = n0 + wn * 64 + ni * 16 + l16;
        if (gcol == lbl) {
          float sy  = sqrtf(fminf(1.f, fmaxf(0.f, 1.f - c * c)));
          float phi = c * COS_M - sy * SIN_M;
          lbl_logit[grow] = S_SC * phi;       // exactly one lane grid-wide
          c = phi;
        }
        rsum += __expf(S_SC * c - 30.0f);     // fixed shift: logits in [-30,30]
      }
      #pragma unroll
      for (int off = 1; off < 16; off <<= 1)
        rsum += __shfl_xor(rsum, off, 64);
      if (l16 == 0) atomicAdd(&rowsum[grow], rsum);
    }
  }

  // ---- fused finish: last finishing block computes the loss (no spin, no co-residency)
  __threadfence();
  if (tid == 0) isLast = (atomicAdd(done, 1) == NACT - 1);
  __syncthreads();
  if (isLast) {
    __threadfence();
    float part = 0.f;
    #pragma unroll
    for (int r = tid; r < B_ROWS; r += 256)
      part += 30.0f + logf(rowsum[r]) - lbl_logit[r];
    #pragma unroll
    for (int off = 32; off >= 1; off >>= 1) part += __shfl_xor(part, off, 64);
    if (lane == 0) ws4[wave] = part;
    __syncthreads();
    if (tid == 0)
      out[0] = (ws4[0] + ws4[1] + ws4[2] + ws4[3]) * (1.0f / (float)B_ROWS);
  }
}

// ---------- launch ----------
extern "C" void kernel_launch(void* const* d_in, const int* in_sizes, int n_in,
                              void* d_out, int out_size, void* d_ws, size_t ws_size,
                              hipStream_t stream) {
  const float* x      = (const float*)d_in[0];
  const float* W      = (const float*)d_in[1];
  const int*   labels = (const int*)d_in[2];
  float* out = (float*)d_out;

  char* ws = (char*)d_ws;
  uint8_t* nx = (uint8_t*)ws;                                       // 1 MB
  uint8_t* nw = (uint8_t*)(ws + (size_t)B_ROWS * D_DIM);            // 16.4 MB
  char* p = ws + (size_t)B_ROWS * D_DIM + (size_t)V_COLS * D_DIM;
  float* rowsum    = (float*)p;  p += (size_t)B_ROWS * 4;           // 8 KB
  float* lbl_logit = (float*)p;  p += (size_t)B_ROWS * 4;           // 8 KB
  int*   done      = (int*)p;                                       // 4 B

  hipLaunchKernelGGL(fused_norm_kernel, dim3((B_ROWS + V_COLS) / 4), dim3(256), 0, stream,
                     x, W, nx, nw, rowsum, done);
  hipLaunchKernelGGL(arc_gemm_kernel, dim3(32 * 16 * 8), dim3(256), 0, stream,
                     nx, nw, labels, rowsum, lbl_logit, done, out);
}

// Round 11
// 176.095 us; speedup vs baseline: 2.2209x; 2.2209x over previous
//
#include <hip/hip_runtime.h>
#include <math.h>
#include <stdint.h>

#define B_ROWS 2048
#define D_DIM  512
#define V_COLS 32000
#define BM 128
#define BN 128
#define BK 64
#define KSTEPS (D_DIM / BK)             // 8
#define NCT    (V_COLS / BN)            // 250 col tiles
#define S_SC   30.0f
#define COS_M  0.8775825618903728f      // cos(0.5)
#define SIN_M  0.479425538604203f       // sin(0.5)

typedef float f32x4 __attribute__((ext_vector_type(4)));
typedef long  i64x2 __attribute__((ext_vector_type(2)));

__device__ __forceinline__ void load16_to_lds(const void* g, void* l) {
  __builtin_amdgcn_global_load_lds(
      (__attribute__((address_space(1))) void*)(g),
      (__attribute__((address_space(3))) void*)(l),
      16, 0, 0);
}

// ---------- kernel 1: fused row L2-normalize (x,W) fp32 -> fp8 e4m3, + zero rowsum/out ----------
__global__ void fused_norm_kernel(const float* __restrict__ x,
                                  const float* __restrict__ W,
                                  uint8_t* __restrict__ nx,
                                  uint8_t* __restrict__ nw,
                                  float* __restrict__ rowsum,
                                  float* __restrict__ out) {
  if (blockIdx.x == 0 && threadIdx.x == 0) out[0] = 0.f;
  if (blockIdx.x < B_ROWS / 256) rowsum[blockIdx.x * 256 + threadIdx.x] = 0.f;
  const int lane = threadIdx.x & 63;
  const int wave = threadIdx.x >> 6;
  const int gr   = blockIdx.x * 4 + wave;
  const float* src;
  uint8_t* dst;
  if (gr < B_ROWS) {
    src = x + (size_t)gr * D_DIM;
    dst = nx + (size_t)gr * D_DIM;
  } else {
    src = W + (size_t)(gr - B_ROWS) * D_DIM;
    dst = nw + (size_t)(gr - B_ROWS) * D_DIM;
  }
  const float4* r4 = (const float4*)src;
  float4 v0 = r4[2 * lane];
  float4 v1 = r4[2 * lane + 1];
  float ss = v0.x*v0.x + v0.y*v0.y + v0.z*v0.z + v0.w*v0.w
           + v1.x*v1.x + v1.y*v1.y + v1.z*v1.z + v1.w*v1.w;
  #pragma unroll
  for (int off = 32; off >= 1; off >>= 1) ss += __shfl_xor(ss, off, 64);
  float inv = 1.0f / fmaxf(sqrtf(ss), 1e-12f);
  int p0 = __builtin_amdgcn_cvt_pk_fp8_f32(v0.x * inv, v0.y * inv, 0, false);
  p0     = __builtin_amdgcn_cvt_pk_fp8_f32(v0.z * inv, v0.w * inv, p0, true);
  int p1 = __builtin_amdgcn_cvt_pk_fp8_f32(v1.x * inv, v1.y * inv, 0, false);
  p1     = __builtin_amdgcn_cvt_pk_fp8_f32(v1.z * inv, v1.w * inv, p1, true);
  ((int2*)dst)[lane] = make_int2(p0, p1);
}

// ---------- kernel 2: fp8 GEMM (nx @ nW^T), BK=64, b128 double-K frags ----------
// R4 skeleton (proven): 2-barrier dbuf K-loop, XCD-exclusive grid swizzle (FETCH ~12 MB
// at fp8), XOR bank swizzle (measured 0 conflicts), fixed-shift softmax epilogue +
// rowsum atomics. fp8 + BK=64 -> each ds_read_b128 feeds TWO MFMAs (low/high 8 B)
// under a K-window permutation applied identically to A and B (contraction
// order-invariant). 8 LDS reads + 32 MFMA per wave-step; 8 barrier-pairs (vs R4's 16).
// R10's fused finish REMOVED: its per-block device-scope __threadfence (L2 writeback)
// is the prime suspect for the 302 us regression. Finish is a separate kernel again.
__global__ __launch_bounds__(256, 4)
void arc_gemm_kernel(const uint8_t* __restrict__ nx,
                     const uint8_t* __restrict__ nw,
                     const int* __restrict__ labels,
                     float* __restrict__ rowsum,
                     float* __restrict__ lbl_logit) {
  __shared__ uint8_t sA[2][BM * BK];   // 2 x 8 KB
  __shared__ uint8_t sB[2][BN * BK];   // 2 x 8 KB

  const int id = blockIdx.x;
  const int ct = ((id >> 7) << 3) | (id & 7);
  if (ct >= NCT) return;
  const int rt = (id >> 3) & 15;
  const int m0 = rt * BM;
  const int n0 = ct * BN;

  const int tid  = threadIdx.x;
  const int wave = tid >> 6;
  const int lane = tid & 63;
  const int wm   = wave >> 1;
  const int wn   = wave & 1;
  const int quad = lane >> 4;
  const int l16  = lane & 15;

  // staging: inst i covers rows i*64 + (tid>>2); slot tid&3 <- global 16B chunk jg.
  const int srow = tid >> 2;
  const int jg   = (tid & 3) ^ ((srow >> 1) & 3);
  const uint8_t* gA = nx + (size_t)(m0 + srow) * D_DIM + jg * 16;
  const uint8_t* gB = nw + (size_t)(n0 + srow) * D_DIM + jg * 16;
  const int ldsOff0 = wave * 1024;          // wave-uniform LDS byte bases
  const int ldsOff1 = 4096 + wave * 1024;

  // frag reads: row stride 64 B, 16B slot XOR swizzle (R4's measured-zero-conflict math)
  const int cSlot = (quad ^ ((l16 >> 1) & 3)) << 4;
  const int aBase = (wm * 64 + l16) * BK + cSlot;   // + mi*16*BK
  const int bBase = (wn * 64 + l16) * BK + cSlot;   // + ni*16*BK

  f32x4 acc[4][4];
  #pragma unroll
  for (int i = 0; i < 4; ++i)
    #pragma unroll
    for (int j = 0; j < 4; ++j) acc[i][j] = (f32x4){0.f, 0.f, 0.f, 0.f};

  // prologue: tile 0 -> buf 0
  load16_to_lds(gA,              &sA[0][ldsOff0]);
  load16_to_lds(gA + 64 * D_DIM, &sA[0][ldsOff1]);
  load16_to_lds(gB,              &sB[0][ldsOff0]);
  load16_to_lds(gB + 64 * D_DIM, &sB[0][ldsOff1]);

  #pragma unroll
  for (int ks = 0; ks < KSTEPS; ++ks) {
    __syncthreads();                          // prev compute done before overwrite
    if (ks + 1 < KSTEPS) {
      const int off = (ks + 1) * BK;
      const int nb  = (ks + 1) & 1;
      load16_to_lds(gA + off,              &sA[nb][ldsOff0]);
      load16_to_lds(gA + 64 * D_DIM + off, &sA[nb][ldsOff1]);
      load16_to_lds(gB + off,              &sB[nb][ldsOff0]);
      load16_to_lds(gB + 64 * D_DIM + off, &sB[nb][ldsOff1]);
    }
    __syncthreads();                          // tile ks resident

    const uint8_t* bA = sA[ks & 1];
    const uint8_t* bB = sB[ks & 1];
    i64x2 a2[4];
    #pragma unroll
    for (int mi = 0; mi < 4; ++mi)
      a2[mi] = *(const i64x2*)(bA + aBase + mi * 16 * BK);
    #pragma unroll
    for (int ni = 0; ni < 4; ++ni) {
      const i64x2 b2 = *(const i64x2*)(bB + bBase + ni * 16 * BK);
      #pragma unroll
      for (int mi = 0; mi < 4; ++mi) {
        acc[mi][ni] = __builtin_amdgcn_mfma_f32_16x16x32_fp8_fp8(a2[mi][0], b2[0], acc[mi][ni], 0, 0, 0);
        acc[mi][ni] = __builtin_amdgcn_mfma_f32_16x16x32_fp8_fp8(a2[mi][1], b2[1], acc[mi][ni], 0, 0, 0);
      }
    }
  }

  // Epilogue (R4-proven). C/D layout: col = lane&15, row = quad*4 + reg.
  const int lblv = labels[m0 + wm * 64 + lane];
  #pragma unroll
  for (int mi = 0; mi < 4; ++mi) {
    #pragma unroll
    for (int r = 0; r < 4; ++r) {
      const int rw   = mi * 16 + quad * 4 + r;
      const int grow = m0 + wm * 64 + rw;
      const int lbl  = __shfl(lblv, rw, 64);
      float rsum = 0.f;
      #pragma unroll
      for (int ni = 0; ni < 4; ++ni) {
        float c = acc[mi][ni][r];
        const int gcol = n0 + wn * 64 + ni * 16 + l16;
        if (gcol == lbl) {
          float sy  = sqrtf(fminf(1.f, fmaxf(0.f, 1.f - c * c)));
          float phi = c * COS_M - sy * SIN_M;
          lbl_logit[grow] = S_SC * phi;       // exactly one lane grid-wide
          c = phi;
        }
        rsum += __expf(S_SC * c - 30.0f);     // fixed shift: logits in [-30,30]
      }
      #pragma unroll
      for (int off = 1; off < 16; off <<= 1)
        rsum += __shfl_xor(rsum, off, 64);
      if (l16 == 0) atomicAdd(&rowsum[grow], rsum);
    }
  }
}

// ---------- kernel 3: per-row loss + global mean ----------
__global__ void arc_finish_kernel(const float* __restrict__ rowsum,
                                  const float* __restrict__ lbl_logit,
                                  float* __restrict__ out) {
  const int row  = blockIdx.x * 256 + threadIdx.x;   // 8 blocks x 256
  const int lane = threadIdx.x & 63;
  const int wave = threadIdx.x >> 6;
  float v = (30.0f + logf(rowsum[row]) - lbl_logit[row]) * (1.0f / (float)B_ROWS);
  #pragma unroll
  for (int off = 32; off >= 1; off >>= 1) v += __shfl_xor(v, off, 64);
  __shared__ float wsum[4];
  if (lane == 0) wsum[wave] = v;
  __syncthreads();
  if (threadIdx.x == 0) atomicAdd(out, wsum[0] + wsum[1] + wsum[2] + wsum[3]);
}

// ---------- launch ----------
extern "C" void kernel_launch(void* const* d_in, const int* in_sizes, int n_in,
                              void* d_out, int out_size, void* d_ws, size_t ws_size,
                              hipStream_t stream) {
  const float* x      = (const float*)d_in[0];
  const float* W      = (const float*)d_in[1];
  const int*   labels = (const int*)d_in[2];
  float* out = (float*)d_out;

  char* ws = (char*)d_ws;
  uint8_t* nx = (uint8_t*)ws;                                       // 1 MB
  uint8_t* nw = (uint8_t*)(ws + (size_t)B_ROWS * D_DIM);            // 16.4 MB
  char* p = ws + (size_t)B_ROWS * D_DIM + (size_t)V_COLS * D_DIM;
  float* rowsum    = (float*)p;  p += (size_t)B_ROWS * 4;           // 8 KB
  float* lbl_logit = (float*)p;                                     // 8 KB

  hipLaunchKernelGGL(fused_norm_kernel, dim3((B_ROWS + V_COLS) / 4), dim3(256), 0, stream,
                     x, W, nx, nw, rowsum, out);
  hipLaunchKernelGGL(arc_gemm_kernel, dim3(32 * 16 * 8), dim3(256), 0, stream,
                     nx, nw, labels, rowsum, lbl_logit);
  hipLaunchKernelGGL(arc_finish_kernel, dim3(B_ROWS / 256), dim3(256), 0, stream,
                     rowsum, lbl_logit, out);
}